// Round 1
// baseline (1003.627 us; speedup 1.0000x reference)
//
#include <hip/hip_runtime.h>
#include <math.h>

#define NROWS 65536
#define DDIM  256
#define KCODES 1024
#define RT 64          // rows per block in argmin kernel
#define KC 16          // k-codes per wave pass

// ws layout (bytes):
//   [0,       262144)  idx       int32[65536]
//   [262144,  266240)  e_norms   f32[1024]
//   [266240,  270336)  counts    int32[1024]
//   [270336,  532480)  partials  f32[65536]

// out layout (f32):
//   [0]            loss
//   [1..16777217)  quantized_st
//   [16777217]     perplexity
//   [16777218..)   encodings (N x K one-hot)

__global__ __launch_bounds__(256) void prep_kernel(const float* __restrict__ emb,
                                                   float* __restrict__ enorm,
                                                   int* __restrict__ counts) {
    int wave = threadIdx.x >> 6;
    int lane = threadIdx.x & 63;
    int row  = blockIdx.x * 4 + wave;   // grid 256 -> 1024 rows
    const float4 v = *(const float4*)(emb + (size_t)row * DDIM + lane * 4);
    float s = v.x * v.x + v.y * v.y + v.z * v.z + v.w * v.w;
    for (int off = 32; off; off >>= 1) s += __shfl_down(s, off, 64);
    if (lane == 0) enorm[row] = s;
    if (blockIdx.x == 0) {
        for (int i = threadIdx.x; i < KCODES; i += 256) counts[i] = 0;
    }
}

__global__ __launch_bounds__(256) void argmin_kernel(const float* __restrict__ x,
                                                     const float* __restrict__ emb,
                                                     const float* __restrict__ enorm,
                                                     int* __restrict__ outidx) {
    // x tile staged TRANSPOSED: xs[d][row], 256*64 floats = 64 KB exactly.
    // Compute reads xs[d*RT + lane] -> lane==row -> banks = lane%32 -> conflict-free.
    __shared__ float xs[DDIM * RT];

    int row0 = blockIdx.x * RT;
    for (int i = threadIdx.x; i < RT * DDIM / 4; i += 256) {
        int r  = i >> 6;     // 0..63 row
        int c4 = i & 63;     // d-group of 4
        float4 v = *(const float4*)(x + (size_t)(row0 + r) * DDIM + c4 * 4);
        xs[(c4 * 4 + 0) * RT + r] = v.x;
        xs[(c4 * 4 + 1) * RT + r] = v.y;
        xs[(c4 * 4 + 2) * RT + r] = v.z;
        xs[(c4 * 4 + 3) * RT + r] = v.w;
    }
    __syncthreads();

    int lane = threadIdx.x & 63;
    // force wave id into SGPR so the e-loads below are provably wave-uniform -> s_load
    int wv = __builtin_amdgcn_readfirstlane(threadIdx.x >> 6);   // 0..3

    float bestv = 3.4e38f;
    int   besti = 0;

    for (int pass = 0; pass < KCODES / (4 * KC); ++pass) {       // 16 passes
        int k0 = wv * (KCODES / 4) + pass * KC;
        const float* __restrict__ eb = emb + (size_t)k0 * DDIM;
        float acc[KC];
#pragma unroll
        for (int k = 0; k < KC; ++k) acc[k] = 0.f;

        for (int d = 0; d < DDIM; d += 4) {
            float x0 = xs[(d + 0) * RT + lane];
            float x1 = xs[(d + 1) * RT + lane];
            float x2 = xs[(d + 2) * RT + lane];
            float x3 = xs[(d + 3) * RT + lane];
#pragma unroll
            for (int k = 0; k < KC; ++k) {
                float4 ev = *(const float4*)(eb + k * DDIM + d);  // uniform -> s_load_dwordx4
                acc[k] = fmaf(x0, ev.x, acc[k]);
                acc[k] = fmaf(x1, ev.y, acc[k]);
                acc[k] = fmaf(x2, ev.z, acc[k]);
                acc[k] = fmaf(x3, ev.w, acc[k]);
            }
        }
#pragma unroll
        for (int k = 0; k < KC; ++k) {
            float s = fmaf(-2.f, acc[k], enorm[k0 + k]);  // ||e||^2 - 2 x.e
            if (s < bestv) { bestv = s; besti = k0 + k; } // strict < keeps lowest k
        }
    }

    // cross-wave argmin per row (4 waves cover disjoint ascending k-ranges)
    __syncthreads();
    float* rv = xs;                 // reuse LDS
    int*   ri = (int*)(xs + 256);
    rv[wv * 64 + lane] = bestv;
    ri[wv * 64 + lane] = besti;
    __syncthreads();
    if (threadIdx.x < 64) {
        float bv = rv[lane];
        int   bi = ri[lane];
#pragma unroll
        for (int w = 1; w < 4; ++w) {
            float v2 = rv[w * 64 + lane];
            int   i2 = ri[w * 64 + lane];
            if (v2 < bv || (v2 == bv && i2 < bi)) { bv = v2; bi = i2; }
        }
        outidx[row0 + lane] = bi;
    }
}

__global__ __launch_bounds__(256) void epilogue_kernel(const float* __restrict__ x,
                                                       const float* __restrict__ emb,
                                                       const int* __restrict__ idxbuf,
                                                       float* __restrict__ out,
                                                       float* __restrict__ partials,
                                                       int* __restrict__ counts) {
    int row = blockIdx.x;
    int t   = threadIdx.x;
    int idx = idxbuf[row];                       // uniform

    float q  = emb[(size_t)idx * DDIM + t];
    float xv = x[(size_t)row * DDIM + t];

    // quantized_st = x + (q - x)  (match reference rounding exactly)
    float diff = q - xv;
    out[1 + (size_t)row * DDIM + t] = xv + diff;

    // encodings row: thread owns k in [4t, 4t+4), float2 stores (base offset is 8B-aligned only)
    float* enc = out + 16777218 + (size_t)row * KCODES;
    int base = t * 4;
    float2 z0 = {0.f, 0.f}, z1 = {0.f, 0.f};
    int r = idx - base;
    if (r == 0) z0.x = 1.f;
    else if (r == 1) z0.y = 1.f;
    else if (r == 2) z1.x = 1.f;
    else if (r == 3) z1.y = 1.f;
    *(float2*)(enc + base)     = z0;
    *(float2*)(enc + base + 2) = z1;

    // per-row sum of squared diff
    float s = diff * diff;
    for (int off = 32; off; off >>= 1) s += __shfl_down(s, off, 64);
    __shared__ float ps[4];
    if ((t & 63) == 0) ps[t >> 6] = s;
    __syncthreads();
    if (t == 0) partials[row] = ps[0] + ps[1] + ps[2] + ps[3];
    if (t == 1) atomicAdd(&counts[idx], 1);
}

__global__ __launch_bounds__(1024) void finalize_kernel(const float* __restrict__ partials,
                                                        const int* __restrict__ counts,
                                                        float* __restrict__ out) {
    __shared__ double sd[16];
    int t = threadIdx.x;

    // loss: deterministic tree reduce of 65536 row partials
    double s = 0.0;
    for (int i = t; i < NROWS; i += 1024) s += (double)partials[i];
    for (int off = 32; off; off >>= 1) s += __shfl_down(s, off, 64);
    if ((t & 63) == 0) sd[t >> 6] = s;
    __syncthreads();
    if (t == 0) {
        double tot = 0.0;
        for (int w = 0; w < 16; ++w) tot += sd[w];
        double mse = tot / ((double)NROWS * (double)DDIM);
        out[0] = (float)(1.25 * mse);   // q_latent + 0.25 * e_latent, both == mse
    }
    __syncthreads();

    // perplexity
    double h;
    {
        int c = counts[t];
        float p = (float)c / (float)NROWS;
        float term = p * logf(p + 1e-10f);
        h = (double)term;
    }
    for (int off = 32; off; off >>= 1) h += __shfl_down(h, off, 64);
    if ((t & 63) == 0) sd[t >> 6] = h;
    __syncthreads();
    if (t == 0) {
        double tot = 0.0;
        for (int w = 0; w < 16; ++w) tot += sd[w];
        out[16777217] = expf((float)(-tot));
    }
}

extern "C" void kernel_launch(void* const* d_in, const int* in_sizes, int n_in,
                              void* d_out, int out_size, void* d_ws, size_t ws_size,
                              hipStream_t stream) {
    const float* x   = (const float*)d_in[0];
    const float* emb = (const float*)d_in[1];
    float* out = (float*)d_out;
    char* ws = (char*)d_ws;

    int*   idx      = (int*)ws;
    float* enorm    = (float*)(ws + 262144);
    int*   counts   = (int*)(ws + 266240);
    float* partials = (float*)(ws + 270336);

    prep_kernel<<<256, 256, 0, stream>>>(emb, enorm, counts);
    argmin_kernel<<<NROWS / RT, 256, 0, stream>>>(x, emb, enorm, idx);
    epilogue_kernel<<<NROWS, 256, 0, stream>>>(x, emb, idx, out, partials, counts);
    finalize_kernel<<<1, 1024, 0, stream>>>(partials, counts, out);
}

// Round 2
// 642.596 us; speedup vs baseline: 1.5618x; 1.5618x over previous
//
#include <hip/hip_runtime.h>
#include <math.h>

#define NROWS 65536
#define DDIM  256
#define KCODES 1024
#define RT 64          // rows per block in argmin kernel
#define KC 8           // k-codes per pass (per wave)
#define NWAVE 16       // waves per argmin block
#define KRANGE (KCODES / NWAVE)   // 64 codes per wave

// ws layout (bytes):
//   [0,       262144)  idx       int32[65536]
//   [262144,  266240)  e_norms   f32[1024]
//   [266240,  270336)  counts    int32[1024]
//   [270336,  532480)  partials  f32[65536]

// out layout (f32):
//   [0]            loss
//   [1..16777217)  quantized_st
//   [16777217]     perplexity
//   [16777218..)   encodings (N x K one-hot)

__global__ __launch_bounds__(256) void prep_kernel(const float* __restrict__ emb,
                                                   float* __restrict__ enorm,
                                                   int* __restrict__ counts) {
    int wave = threadIdx.x >> 6;
    int lane = threadIdx.x & 63;
    int row  = blockIdx.x * 4 + wave;   // grid 256 -> 1024 rows
    const float4 v = *(const float4*)(emb + (size_t)row * DDIM + lane * 4);
    float s = v.x * v.x + v.y * v.y + v.z * v.z + v.w * v.w;
    for (int off = 32; off; off >>= 1) s += __shfl_down(s, off, 64);
    if (lane == 0) enorm[row] = s;
    if (blockIdx.x == 0) {
        for (int i = threadIdx.x; i < KCODES; i += 256) counts[i] = 0;
    }
}

// xs layout: d-pair p = d>>1 in [0,128). word index = p*128 + ((2r) ^ (2*(p&15))) + (d&1).
// 16384 words = 64 KB exactly. Reads (lane=r varies, p fixed) hit the b64 floor;
// staging writes (r fixed, p varies) are 8-way instead of 32-way.
__device__ __forceinline__ int xs_idx(int p, int r) {
    return p * 128 + ((2 * r) ^ (2 * (p & 15)));
}

__global__ __launch_bounds__(1024, 8) void argmin_kernel(const float* __restrict__ x,
                                                         const float* __restrict__ emb,
                                                         const float* __restrict__ enorm,
                                                         int* __restrict__ outidx) {
    __shared__ float xs[DDIM * RT];   // 64 KB, swizzled pair layout

    int row0 = blockIdx.x * RT;
    // stage x tile transposed (pair-swizzled): 4096 float4 loads across 1024 threads
    for (int i = threadIdx.x; i < RT * DDIM / 4; i += 1024) {
        int r  = i >> 6;     // 0..63 row
        int c4 = i & 63;     // d-group of 4
        float4 v = *(const float4*)(x + (size_t)(row0 + r) * DDIM + c4 * 4);
        int p0 = 2 * c4, p1 = 2 * c4 + 1;
        *(float2*)(xs + xs_idx(p0, r)) = make_float2(v.x, v.y);
        *(float2*)(xs + xs_idx(p1, r)) = make_float2(v.z, v.w);
    }
    __syncthreads();

    int lane = threadIdx.x & 63;      // = row within tile
    // wave id in SGPR so e/enorm loads are provably wave-uniform
    int wv = __builtin_amdgcn_readfirstlane(threadIdx.x >> 6);   // 0..15

    float bestv = 3.4e38f;
    int   besti = 0;

    for (int pass = 0; pass < KRANGE / KC; ++pass) {             // 8 passes
        int k0 = wv * KRANGE + pass * KC;
        const float* __restrict__ eb = emb + (size_t)k0 * DDIM;
        float acc[KC];
#pragma unroll
        for (int k = 0; k < KC; ++k) acc[k] = 0.f;

        for (int q = 0; q < DDIM / 4; ++q) {                     // 64 q-steps, d = 4q..4q+3
            int p0 = 2 * q, p1 = 2 * q + 1;
            float2 a  = *(const float2*)(xs + xs_idx(p0, lane));
            float2 b2 = *(const float2*)(xs + xs_idx(p1, lane));
#pragma unroll
            for (int k = 0; k < KC; ++k) {
                float4 ev = *(const float4*)(eb + k * DDIM + 4 * q);  // wave-uniform
                acc[k] = fmaf(a.x,  ev.x, acc[k]);
                acc[k] = fmaf(a.y,  ev.y, acc[k]);
                acc[k] = fmaf(b2.x, ev.z, acc[k]);
                acc[k] = fmaf(b2.y, ev.w, acc[k]);
            }
        }
#pragma unroll
        for (int k = 0; k < KC; ++k) {
            float s = fmaf(-2.f, acc[k], enorm[k0 + k]);  // ||e||^2 - 2 x.e
            if (s < bestv) { bestv = s; besti = k0 + k; } // strict < keeps lowest k
        }
    }

    // cross-wave argmin per row (16 waves cover disjoint ascending k-ranges)
    __syncthreads();
    float* rv = xs;                       // reuse LDS
    int*   ri = (int*)(xs + NWAVE * 64);
    rv[wv * 64 + lane] = bestv;
    ri[wv * 64 + lane] = besti;
    __syncthreads();
    if (threadIdx.x < 64) {
        float bv = rv[lane];
        int   bi = ri[lane];
#pragma unroll
        for (int w = 1; w < NWAVE; ++w) {
            float v2 = rv[w * 64 + lane];
            int   i2 = ri[w * 64 + lane];
            if (v2 < bv || (v2 == bv && i2 < bi)) { bv = v2; bi = i2; }
        }
        outidx[row0 + lane] = bi;
    }
}

__global__ __launch_bounds__(256) void epilogue_kernel(const float* __restrict__ x,
                                                       const float* __restrict__ emb,
                                                       const int* __restrict__ idxbuf,
                                                       float* __restrict__ out,
                                                       float* __restrict__ partials,
                                                       int* __restrict__ counts) {
    int row = blockIdx.x;
    int t   = threadIdx.x;
    int idx = idxbuf[row];                       // uniform

    float q  = emb[(size_t)idx * DDIM + t];
    float xv = x[(size_t)row * DDIM + t];

    // quantized_st = x + (q - x)  (match reference rounding exactly)
    float diff = q - xv;
    out[1 + (size_t)row * DDIM + t] = xv + diff;

    // encodings row: thread owns k in [4t, 4t+4), float2 stores (base offset is 8B-aligned only)
    float* enc = out + 16777218 + (size_t)row * KCODES;
    int base = t * 4;
    float2 z0 = {0.f, 0.f}, z1 = {0.f, 0.f};
    int r = idx - base;
    if (r == 0) z0.x = 1.f;
    else if (r == 1) z0.y = 1.f;
    else if (r == 2) z1.x = 1.f;
    else if (r == 3) z1.y = 1.f;
    *(float2*)(enc + base)     = z0;
    *(float2*)(enc + base + 2) = z1;

    // per-row sum of squared diff
    float s = diff * diff;
    for (int off = 32; off; off >>= 1) s += __shfl_down(s, off, 64);
    __shared__ float ps[4];
    if ((t & 63) == 0) ps[t >> 6] = s;
    __syncthreads();
    if (t == 0) partials[row] = ps[0] + ps[1] + ps[2] + ps[3];
    if (t == 1) atomicAdd(&counts[idx], 1);
}

__global__ __launch_bounds__(1024) void finalize_kernel(const float* __restrict__ partials,
                                                        const int* __restrict__ counts,
                                                        float* __restrict__ out) {
    __shared__ double sd[16];
    int t = threadIdx.x;

    // loss: deterministic tree reduce of 65536 row partials
    double s = 0.0;
    for (int i = t; i < NROWS; i += 1024) s += (double)partials[i];
    for (int off = 32; off; off >>= 1) s += __shfl_down(s, off, 64);
    if ((t & 63) == 0) sd[t >> 6] = s;
    __syncthreads();
    if (t == 0) {
        double tot = 0.0;
        for (int w = 0; w < 16; ++w) tot += sd[w];
        double mse = tot / ((double)NROWS * (double)DDIM);
        out[0] = (float)(1.25 * mse);   // q_latent + 0.25 * e_latent, both == mse
    }
    __syncthreads();

    // perplexity
    double h;
    {
        int c = counts[t];
        float p = (float)c / (float)NROWS;
        float term = p * logf(p + 1e-10f);
        h = (double)term;
    }
    for (int off = 32; off; off >>= 1) h += __shfl_down(h, off, 64);
    if ((t & 63) == 0) sd[t >> 6] = h;
    __syncthreads();
    if (t == 0) {
        double tot = 0.0;
        for (int w = 0; w < 16; ++w) tot += sd[w];
        out[16777217] = expf((float)(-tot));
    }
}

extern "C" void kernel_launch(void* const* d_in, const int* in_sizes, int n_in,
                              void* d_out, int out_size, void* d_ws, size_t ws_size,
                              hipStream_t stream) {
    const float* x   = (const float*)d_in[0];
    const float* emb = (const float*)d_in[1];
    float* out = (float*)d_out;
    char* ws = (char*)d_ws;

    int*   idx      = (int*)ws;
    float* enorm    = (float*)(ws + 262144);
    int*   counts   = (int*)(ws + 266240);
    float* partials = (float*)(ws + 270336);

    prep_kernel<<<256, 256, 0, stream>>>(emb, enorm, counts);
    argmin_kernel<<<NROWS / RT, 1024, 0, stream>>>(x, emb, enorm, idx);
    epilogue_kernel<<<NROWS, 256, 0, stream>>>(x, emb, idx, out, partials, counts);
    finalize_kernel<<<1, 1024, 0, stream>>>(partials, counts, out);
}

// Round 3
// 210.406 us; speedup vs baseline: 4.7700x; 3.0541x over previous
//
#include <hip/hip_runtime.h>
#include <math.h>

#define NROWS 65536
#define DDIM  256
#define KCODES 1024
#define CHUNK 64                         // codes per chunk
#define NCHUNK (KCODES / CHUNK)          // 16
#define KSTEPS 17                        // 16 real K-steps + 1 enorm step
#define PLANE_BYTES (KSTEPS * 2 * CHUNK * 16)   // 34816
#define CHUNK_BYTES (2 * PLANE_BYTES)           // 69632 (hi+lo planes)
#define ROWS_PER_BLOCK 256
#define ROWS_PER_WAVE 32

typedef _Float16 half8 __attribute__((ext_vector_type(8)));
typedef float    f32x16 __attribute__((ext_vector_type(16)));

// ws layout (bytes):
//   [0,       262144)  idx       int32[65536]
//   [266240,  270336)  counts    int32[1024]
//   [270336,  532480)  partials  f32[65536]
// out scratch (inside encodings region, overwritten later by epilogue):
//   pack = (char*)(out + 16777220), 16 chunks x 69632 B = 1.06 MB, 16B-aligned

// ---------------- prep: pack emb into fragment-ready f16 hi/lo planes ----------------
// LDS image per chunk: offset(plane, ks, khalf, code, j) =
//   plane*34816 + ks*2048 + khalf*1024 + code*16 + j*2
__global__ __launch_bounds__(256) void pack_emb_kernel(const float* __restrict__ emb,
                                                       char* __restrict__ pack) {
    int tid  = blockIdx.x * 256 + threadIdx.x;   // 32768 threads
    int code = tid >> 5;                          // 0..1023
    int g    = tid & 31;                          // 8-dim group: d0 = g*8
    int ks = g >> 1, kh = g & 1;
    int c = code >> 6, ci = code & 63;
    const float* src = emb + (size_t)code * DDIM + g * 8;
    half8 hi, lo;
#pragma unroll
    for (int j = 0; j < 8; ++j) {
        float v = src[j];
        _Float16 h = (_Float16)v;
        hi[j] = h;
        lo[j] = (_Float16)(v - (float)h);
    }
    size_t off = (size_t)c * CHUNK_BYTES + (size_t)ks * 2048 + (size_t)kh * 1024 + (size_t)ci * 16;
    *(half8*)(pack + off) = hi;
    *(half8*)(pack + off + PLANE_BYTES) = lo;
}

// enorm -> ks=16 slots as 3-term f16 split of -||e||^2/2; also zero counts
__global__ __launch_bounds__(256) void norm_emb_kernel(const float* __restrict__ emb,
                                                       char* __restrict__ pack,
                                                       int* __restrict__ counts) {
    int w = threadIdx.x >> 6, lane = threadIdx.x & 63;
    int code = blockIdx.x * 4 + w;                // grid 256 -> 1024 codes
    float4 v = *(const float4*)(emb + (size_t)code * DDIM + lane * 4);
    float s = v.x * v.x + v.y * v.y + v.z * v.z + v.w * v.w;
    for (int off = 32; off; off >>= 1) s += __shfl_down(s, off, 64);
    s = __shfl(s, 0, 64);
    int c = code >> 6, ci = code & 63;
    size_t base = (size_t)c * CHUNK_BYTES + (size_t)16 * 2048 + (size_t)ci * 16;
    if (lane < 4) {
        half8 val = (half8)(_Float16)0.0f;
        if (lane == 0) {
            float xv = -0.5f * s;
            _Float16 t1 = (_Float16)xv; float r = xv - (float)t1;
            _Float16 t2 = (_Float16)r;  r -= (float)t2;
            _Float16 t3 = (_Float16)r;
            val[0] = t1; val[1] = t2; val[2] = t3;
        }
        // lane0: hi kh0 (data); lane1: hi kh1 = 0; lane2: lo kh0 = 0; lane3: lo kh1 = 0
        size_t off = base + (size_t)(lane & 1) * 1024 + (size_t)(lane >> 1) * PLANE_BYTES;
        *(half8*)(pack + off) = val;
    }
    if (blockIdx.x == 0)
        for (int i = threadIdx.x; i < KCODES; i += 256) counts[i] = 0;
}

// ---------------- argmin via 32x32x16 f16 MFMA, 3-pass hi/lo split ----------------
__global__ __launch_bounds__(512, 2) void argmin_mfma(const float* __restrict__ x,
                                                      const char* __restrict__ pack,
                                                      int* __restrict__ outidx) {
    extern __shared__ char smem[];     // 2 * 69632 = 139264 B
    const int tid  = threadIdx.x;
    const int lane = tid & 63;
    const int w    = __builtin_amdgcn_readfirstlane(tid >> 6);   // 0..7
    const int kh   = lane >> 5;        // k-half
    const int l31  = lane & 31;
    const int row  = blockIdx.x * ROWS_PER_BLOCK + w * ROWS_PER_WAVE + l31;

    // B-frags (x rows) -> registers, f16 hi/lo split. 34 x half8 = 136 VGPRs.
    half8 bh[KSTEPS], bl[KSTEPS];
#pragma unroll
    for (int ks = 0; ks < 16; ++ks) {
        const float* p = x + (size_t)row * DDIM + ks * 16 + kh * 8;
        float4 v0 = *(const float4*)p;
        float4 v1 = *(const float4*)(p + 4);
        float vv[8] = {v0.x, v0.y, v0.z, v0.w, v1.x, v1.y, v1.z, v1.w};
#pragma unroll
        for (int j = 0; j < 8; ++j) {
            _Float16 h = (_Float16)vv[j];
            bh[ks][j] = h;
            bl[ks][j] = (_Float16)(vv[j] - (float)h);
        }
    }
    {
        half8 z = (half8)(_Float16)0.0f;
        bh[16] = z; bl[16] = z;
        if (kh == 0) {   // e-side ks16 data lives in k=0..2 only
            bh[16][0] = (_Float16)1.0f;
            bh[16][1] = (_Float16)1.0f;
            bh[16][2] = (_Float16)1.0f;
        }
    }

    char* buf0 = smem;
    char* buf1 = smem + CHUNK_BYTES;

    // prologue: DMA chunk 0
    for (int i = w; i < CHUNK_BYTES / 1024; i += 8)
        __builtin_amdgcn_global_load_lds(
            (const __attribute__((address_space(1))) void*)(pack + i * 1024 + lane * 16),
            (__attribute__((address_space(3))) void*)(buf0 + i * 1024), 16, 0, 0);
    __syncthreads();

    float bestv = -3.4e38f;
    int   besti = 0;
    const int rbase = 4 * kh;

    for (int c = 0; c < NCHUNK; ++c) {
        char* buf = (c & 1) ? buf1 : buf0;
        if (c + 1 < NCHUNK) {
            const char* src = pack + (size_t)(c + 1) * CHUNK_BYTES;
            char* dst = (c & 1) ? buf0 : buf1;
            for (int i = w; i < CHUNK_BYTES / 1024; i += 8)
                __builtin_amdgcn_global_load_lds(
                    (const __attribute__((address_space(1))) void*)(src + i * 1024 + lane * 16),
                    (__attribute__((address_space(3))) void*)(dst + i * 1024), 16, 0, 0);
        }
        f32x16 acc0 = (f32x16)0.0f;
        f32x16 acc1 = (f32x16)0.0f;
#pragma unroll
        for (int ks = 0; ks < KSTEPS; ++ks) {
            const char* base = buf + ks * 2048 + kh * 1024;
            half8 ah0 = *(const half8*)(base + l31 * 16);                       // codes tile0
            half8 ah1 = *(const half8*)(base + 512 + l31 * 16);                 // codes tile1
            half8 al0 = *(const half8*)(base + PLANE_BYTES + l31 * 16);
            half8 al1 = *(const half8*)(base + PLANE_BYTES + 512 + l31 * 16);
            acc0 = __builtin_amdgcn_mfma_f32_32x32x16_f16(ah0, bh[ks], acc0, 0, 0, 0);
            acc1 = __builtin_amdgcn_mfma_f32_32x32x16_f16(ah1, bh[ks], acc1, 0, 0, 0);
            acc0 = __builtin_amdgcn_mfma_f32_32x32x16_f16(ah0, bl[ks], acc0, 0, 0, 0);
            acc1 = __builtin_amdgcn_mfma_f32_32x32x16_f16(ah1, bl[ks], acc1, 0, 0, 0);
            acc0 = __builtin_amdgcn_mfma_f32_32x32x16_f16(al0, bh[ks], acc0, 0, 0, 0);
            acc1 = __builtin_amdgcn_mfma_f32_32x32x16_f16(al1, bh[ks], acc1, 0, 0, 0);
        }
        // acc = x.e - ||e||^2/2 ; argmax == argmin of distance
        int cb = c * CHUNK;
#pragma unroll
        for (int r = 0; r < 16; ++r) {
            int co = cb + (r & 3) + 8 * (r >> 2) + rbase;   // C-layout row (verified m74/m101)
            float v0 = acc0[r];
            if (v0 > bestv || (v0 == bestv && co < besti)) { bestv = v0; besti = co; }
            float v1 = acc1[r];
            int co1 = co + 32;
            if (v1 > bestv || (v1 == bestv && co1 < besti)) { bestv = v1; besti = co1; }
        }
        __syncthreads();   // drains DMA (vmcnt) + makes next buffer safe
    }

    // combine the two k-half partners (same x-row, disjoint code sets)
    float pv = __shfl_xor(bestv, 32, 64);
    int   pi = __shfl_xor(besti, 32, 64);
    if (pv > bestv || (pv == bestv && pi < besti)) { bestv = pv; besti = pi; }
    if (kh == 0) outidx[row] = besti;
}

// ---------------- epilogue + finalize (unchanged from round 2) ----------------
__global__ __launch_bounds__(256) void epilogue_kernel(const float* __restrict__ x,
                                                       const float* __restrict__ emb,
                                                       const int* __restrict__ idxbuf,
                                                       float* __restrict__ out,
                                                       float* __restrict__ partials,
                                                       int* __restrict__ counts) {
    int row = blockIdx.x;
    int t   = threadIdx.x;
    int idx = idxbuf[row];

    float q  = emb[(size_t)idx * DDIM + t];
    float xv = x[(size_t)row * DDIM + t];

    float diff = q - xv;
    out[1 + (size_t)row * DDIM + t] = xv + diff;

    float* enc = out + 16777218 + (size_t)row * KCODES;
    int base = t * 4;
    float2 z0 = {0.f, 0.f}, z1 = {0.f, 0.f};
    int r = idx - base;
    if (r == 0) z0.x = 1.f;
    else if (r == 1) z0.y = 1.f;
    else if (r == 2) z1.x = 1.f;
    else if (r == 3) z1.y = 1.f;
    *(float2*)(enc + base)     = z0;
    *(float2*)(enc + base + 2) = z1;

    float s = diff * diff;
    for (int off = 32; off; off >>= 1) s += __shfl_down(s, off, 64);
    __shared__ float ps[4];
    if ((t & 63) == 0) ps[t >> 6] = s;
    __syncthreads();
    if (t == 0) partials[row] = ps[0] + ps[1] + ps[2] + ps[3];
    if (t == 1) atomicAdd(&counts[idx], 1);
}

__global__ __launch_bounds__(1024) void finalize_kernel(const float* __restrict__ partials,
                                                        const int* __restrict__ counts,
                                                        float* __restrict__ out) {
    __shared__ double sd[16];
    int t = threadIdx.x;

    double s = 0.0;
    for (int i = t; i < NROWS; i += 1024) s += (double)partials[i];
    for (int off = 32; off; off >>= 1) s += __shfl_down(s, off, 64);
    if ((t & 63) == 0) sd[t >> 6] = s;
    __syncthreads();
    if (t == 0) {
        double tot = 0.0;
        for (int wv = 0; wv < 16; ++wv) tot += sd[wv];
        double mse = tot / ((double)NROWS * (double)DDIM);
        out[0] = (float)(1.25 * mse);
    }
    __syncthreads();

    double h;
    {
        int c = counts[t];
        float p = (float)c / (float)NROWS;
        float term = p * logf(p + 1e-10f);
        h = (double)term;
    }
    for (int off = 32; off; off >>= 1) h += __shfl_down(h, off, 64);
    if ((t & 63) == 0) sd[t >> 6] = h;
    __syncthreads();
    if (t == 0) {
        double tot = 0.0;
        for (int wv = 0; wv < 16; ++wv) tot += sd[wv];
        out[16777217] = expf((float)(-tot));
    }
}

extern "C" void kernel_launch(void* const* d_in, const int* in_sizes, int n_in,
                              void* d_out, int out_size, void* d_ws, size_t ws_size,
                              hipStream_t stream) {
    const float* x   = (const float*)d_in[0];
    const float* emb = (const float*)d_in[1];
    float* out = (float*)d_out;
    char* ws = (char*)d_ws;

    int*   idx      = (int*)ws;
    int*   counts   = (int*)(ws + 266240);
    float* partials = (float*)(ws + 270336);

    // scratch inside the encodings output region (epilogue overwrites it afterwards);
    // out+16777220 floats = byte 67108880, 16B-aligned
    char* pack = (char*)(out + 16777220);

    hipFuncSetAttribute((const void*)argmin_mfma,
                        hipFuncAttributeMaxDynamicSharedMemorySize, 2 * CHUNK_BYTES);

    pack_emb_kernel<<<128, 256, 0, stream>>>(emb, pack);
    norm_emb_kernel<<<256, 256, 0, stream>>>(emb, pack, counts);
    argmin_mfma<<<NROWS / ROWS_PER_BLOCK, 512, 2 * CHUNK_BYTES, stream>>>(x, pack, idx);
    epilogue_kernel<<<NROWS, 256, 0, stream>>>(x, emb, idx, out, partials, counts);
    finalize_kernel<<<1, 1024, 0, stream>>>(partials, counts, out);
}